// Round 1
// baseline (1111.919 us; speedup 1.0000x reference)
//
#include <hip/hip_runtime.h>
#include <cmath>

#define B_ 32
#define S_ 1024
#define D_ 256
#define K_ 1024
#define N_ (B_*S_)

// ---- output layout (floats) ----
#define O_Q     0
#define O_LOSS  8388608
#define O_PERP  8388609
#define O_IDX   8388610
#define O_NW    8421378
#define O_NEW   8683522
#define O_NCS   8945666

// ---- workspace layout (bytes) ----
#define OFF_FEATS 0ull                  // N*D*4 = 33554432
#define OFF_A     33554432ull           // N*8
#define OFF_BW    33816576ull           // K*8
#define OFF_SAMP  33824768ull           // N*8
#define OFF_IDXF  34086912ull           // N*4
#define OFF_ENC   34217984ull           // N*4
#define OFF_MIN1  34349056ull           // N*4
#define OFF_MIN2  34480128ull           // N*4
#define OFF_I1    34611200ull           // N*4
#define OFF_CNT   34742272ull           // K*4   (zeroed)
#define OFF_DW    34746368ull           // K*D*4 (zeroed)
#define OFF_LOSS  35794944ull           // 8     (zeroed)
#define OFF_CSF   35794952ull           // K*4
#define ZERO_BEGIN OFF_CNT
#define ZERO_BYTES (35794952ull - 34742272ull)

#define MARGIN 1e-4f

// ---------------- LayerNorm (f64 internal, f32 feats out, f64 sum(f^2)) -------------
__global__ void k_ln(const float* __restrict__ x, const float* __restrict__ g,
                     const float* __restrict__ bta, float* __restrict__ feats,
                     double* __restrict__ A) {
    int n = blockIdx.x; int lane = threadIdx.x;
    const float* row = x + (size_t)n * D_;
    double xv[4], gv[4], bv[4];
#pragma unroll
    for (int i = 0; i < 4; i++) {
        int d = lane + 64 * i;
        xv[i] = row[d]; gv[i] = g[d]; bv[i] = bta[d];
    }
    double s = xv[0] + xv[1] + xv[2] + xv[3];
    for (int m = 32; m > 0; m >>= 1) s += __shfl_xor(s, m, 64);
    double mu = s / 256.0;
    double vs = 0.0;
#pragma unroll
    for (int i = 0; i < 4; i++) { double c = xv[i] - mu; vs += c * c; }
    for (int m = 32; m > 0; m >>= 1) vs += __shfl_xor(vs, m, 64);
    double var = vs / 256.0;
    double inv = 1.0 / sqrt(var + 1e-5);
    float* frow = feats + (size_t)n * D_;
    double a = 0.0;
#pragma unroll
    for (int i = 0; i < 4; i++) {
        int d = lane + 64 * i;
        double f = (xv[i] - mu) * inv * gv[i] + bv[i];
        frow[d] = (float)f;
        a += f * f;
    }
    for (int m = 32; m > 0; m >>= 1) a += __shfl_xor(a, m, 64);
    if (lane == 0) A[n] = a;
}

// ---------------- ||w_k||^2 in f64 -------------
__global__ void k_bw(const float* __restrict__ w, double* __restrict__ Bw) {
    int k = blockIdx.x; int lane = threadIdx.x;
    double s = 0.0;
#pragma unroll
    for (int i = 0; i < 4; i++) {
        double v = w[(size_t)k * D_ + lane + 64 * i];
        s += v * v;
    }
    for (int m = 32; m > 0; m >>= 1) s += __shfl_xor(s, m, 64);
    if (lane == 0) Bw[k] = s;
}

// ---------------- Phase 1: fp32 GEMM + fused top-2 min per row -------------
// block: 256 thr (tx=code 16, ty=row 16), tile 64 rows x 64 codes, D chunked by 32
__launch_bounds__(256)
__global__ void k_phase1(const float* __restrict__ feats, const float* __restrict__ w,
                         const double* __restrict__ Bw,
                         float* __restrict__ min1o, float* __restrict__ min2o,
                         int* __restrict__ i1o) {
    __shared__ float sF[64][36];
    __shared__ float sW[64][36];
    __shared__ float tm1[64][16];
    __shared__ float tm2[64][16];
    __shared__ int   tc1[64][16];
    __shared__ float rm1[64], rm2[64];
    __shared__ int   rc1[64];

    int tid = threadIdx.x;
    int tx = tid & 15, ty = tid >> 4;
    int row0 = blockIdx.x * 64;
    if (tid < 64) { rm1[tid] = 3.0e38f; rm2[tid] = 3.0e38f; rc1[tid] = 0; }

    for (int k0 = 0; k0 < K_; k0 += 64) {
        float acc[4][4] = {};
        for (int d0 = 0; d0 < D_; d0 += 32) {
            __syncthreads();
#pragma unroll
            for (int i = 0; i < 8; i++) {
                int e = tid + 256 * i; int r = e >> 5; int dd = e & 31;
                sF[r][dd] = feats[(size_t)(row0 + r) * D_ + d0 + dd];
                sW[r][dd] = w[(size_t)(k0 + r) * D_ + d0 + dd];
            }
            __syncthreads();
#pragma unroll
            for (int dd = 0; dd < 32; dd += 4) {
                float4 fa[4], fb[4];
#pragma unroll
                for (int i = 0; i < 4; i++) fa[i] = *(const float4*)&sF[4 * ty + i][dd];
#pragma unroll
                for (int j = 0; j < 4; j++) fb[j] = *(const float4*)&sW[tx + 16 * j][dd];
#pragma unroll
                for (int i = 0; i < 4; i++)
#pragma unroll
                    for (int j = 0; j < 4; j++)
                        acc[i][j] += fa[i].x * fb[j].x + fa[i].y * fb[j].y
                                   + fa[i].z * fb[j].z + fa[i].w * fb[j].w;
            }
        }
        float Bc[4];
#pragma unroll
        for (int j = 0; j < 4; j++) Bc[j] = (float)Bw[k0 + tx + 16 * j];
#pragma unroll
        for (int i = 0; i < 4; i++) {
            float m1 = 3.0e38f, m2 = 3.0e38f; int c1 = -1;
#pragma unroll
            for (int j = 0; j < 4; j++) {
                float sv = fmaf(-2.0f, acc[i][j], Bc[j]);
                int c = k0 + tx + 16 * j;
                if (sv < m1 || (sv == m1 && c < c1)) { m2 = m1; m1 = sv; c1 = c; }
                else if (sv < m2) m2 = sv;
            }
            tm1[4 * ty + i][tx] = m1; tm2[4 * ty + i][tx] = m2; tc1[4 * ty + i][tx] = c1;
        }
        __syncthreads();
        if (tid < 64) {
            float M1 = rm1[tid], M2 = rm2[tid]; int C1 = rc1[tid];
            for (int t = 0; t < 16; t++) {
                float m1 = tm1[tid][t], m2 = tm2[tid][t]; int c = tc1[tid][t];
                if (m1 < M1 || (m1 == M1 && c < C1)) {
                    M2 = (m2 < M1) ? m2 : M1; M1 = m1; C1 = c;
                } else if (m1 < M2) M2 = m1;
            }
            rm1[tid] = M1; rm2[tid] = M2; rc1[tid] = C1;
        }
        __syncthreads();
    }
    if (tid < 64) {
        min1o[row0 + tid] = rm1[tid];
        min2o[row0 + tid] = rm2[tid];
        i1o[row0 + tid]   = rc1[tid];
    }
}

// ---------------- Phase 2: exact f64 distance for winner (or full rescan) -------------
__global__ void k_phase2(const float* __restrict__ feats, const float* __restrict__ w,
                         const double* __restrict__ Bw, const double* __restrict__ A,
                         const float* __restrict__ min1, const float* __restrict__ min2,
                         const int* __restrict__ i1a,
                         double* __restrict__ sampled, int* __restrict__ idxf) {
    int n = blockIdx.x; int lane = threadIdx.x;
    float m1 = min1[n], m2 = min2[n]; int c1 = i1a[n];
    const float* frow = feats + (size_t)n * D_;

    if (m2 - m1 > MARGIN) {
        const float* wr = w + (size_t)c1 * D_;
        double s = 0.0;
#pragma unroll
        for (int i = 0; i < 4; i++) {
            int d = lane + 64 * i;
            s += (double)frow[d] * (double)wr[d];
        }
        for (int m = 32; m > 0; m >>= 1) s += __shfl_xor(s, m, 64);
        if (lane == 0) {
            double dd = (A[n] + Bw[c1]) - 2.0 * s;
            sampled[n] = dd; idxf[n] = c1;
        }
    } else {
        // rare slow path: exact f64 scan over all codes, lane-strided over codes
        double bm = 1.0e300, bs = 0.0; int bc = 0x7fffffff;
        for (int c = lane; c < K_; c += 64) {
            const float* wr = w + (size_t)c * D_;
            double s = 0.0;
            for (int d = 0; d < D_; d++) s += (double)frow[d] * (double)wr[d];
            double dist = Bw[c] - 2.0 * s;
            if (dist < bm || (dist == bm && c < bc)) { bm = dist; bc = c; bs = s; }
        }
        for (int m = 32; m > 0; m >>= 1) {
            double om = __shfl_xor(bm, m, 64);
            double os = __shfl_xor(bs, m, 64);
            int    oc = __shfl_xor(bc, m, 64);
            if (om < bm || (om == bm && oc < bc)) { bm = om; bc = oc; bs = os; }
        }
        if (lane == 0) {
            double dd = (A[n] + Bw[bc]) - 2.0 * bs;
            sampled[n] = dd; idxf[n] = bc;
        }
    }
}

// ---------------- stable argsort per batch row (bitonic on (val,idx)) + enc gather ----
__launch_bounds__(1024)
__global__ void k_sort(const double* __restrict__ sampled, const int* __restrict__ idxf,
                       int* __restrict__ enc) {
    __shared__ double val[1024];
    __shared__ int    sid[1024];
    int b = blockIdx.x, t = threadIdx.x;
    val[t] = sampled[(size_t)b * S_ + t];
    sid[t] = t;
    __syncthreads();
    for (int k = 2; k <= 1024; k <<= 1) {
        for (int j = k >> 1; j > 0; j >>= 1) {
            int p = t ^ j;
            if (p > t) {
                double v0 = val[t], v1 = val[p];
                int i0 = sid[t], i1 = sid[p];
                bool gtv = (v0 > v1) || (v0 == v1 && i0 > i1);
                bool asc = ((t & k) == 0);
                if (asc ? gtv : !gtv) {
                    val[t] = v1; val[p] = v0; sid[t] = i1; sid[p] = i0;
                }
            }
            __syncthreads();
        }
    }
    // faithful reference bug: order value (in [0,S)) indexes flat idx vector
    enc[(size_t)b * S_ + t] = idxf[sid[t]];
}

// ---------------- scatter: quantized, enc out, counts, dw, loss -------------
__global__ void k_scatter(const float* __restrict__ x, const float* __restrict__ w,
                          const int* __restrict__ enc, float* __restrict__ out,
                          unsigned* __restrict__ counts, float* __restrict__ dw,
                          double* __restrict__ lossAcc) {
    int n = blockIdx.x, lane = threadIdx.x;
    int e = enc[n];
    const float* wr = w + (size_t)e * D_;
    const float* xr = x + (size_t)n * D_;
    float* qr = out + O_Q + (size_t)n * D_;
    double ls = 0.0;
#pragma unroll
    for (int i = 0; i < 4; i++) {
        int d = lane + 64 * i;
        float q = wr[d], xv = xr[d];
        qr[d] = q;
        double df = (double)q - (double)xv;
        ls += df * df;
        atomicAdd(&dw[(size_t)e * D_ + d], xv);
    }
    for (int m = 32; m > 0; m >>= 1) ls += __shfl_xor(ls, m, 64);
    if (lane == 0) {
        out[O_IDX + n] = (float)e;
        atomicAdd(&counts[e], 1u);
        atomicAdd(lossAcc, ls);
    }
}

// ---------------- finalize: cs smoothing, loss, perplexity -------------
__launch_bounds__(1024)
__global__ void k_final(const unsigned* __restrict__ counts, const float* __restrict__ ema_cs,
                        const double* __restrict__ lossAcc, float* __restrict__ out,
                        float* __restrict__ cs_final) {
    __shared__ double red[1024];
    int t = threadIdx.x;
    unsigned c = counts[t];
    float cf = (float)c;
    float cs0 = ema_cs[t] * 0.99f + 0.01f * cf;
    red[t] = (double)cs0;
    __syncthreads();
    for (int s = 512; s > 0; s >>= 1) {
        if (t < s) red[t] += red[t + s];
        __syncthreads();
    }
    double ntot = red[0];
    __syncthreads();
    double csf = ((double)cs0 + 1e-5) / (ntot + 1024.0 * 1e-5) * ntot;
    out[O_NCS + t] = (float)csf;
    cs_final[t] = (float)csf;
    double p = (double)cf / 32768.0;
    red[t] = -p * log(p + 1e-10);
    __syncthreads();
    for (int s = 512; s > 0; s >>= 1) {
        if (t < s) red[t] += red[t + s];
        __syncthreads();
    }
    if (t == 0) {
        out[O_PERP] = (float)exp(red[0]);
        out[O_LOSS] = (float)(1.25 * lossAcc[0] / 8388608.0);
    }
}

// ---------------- new_ema_w / new_weight -------------
__global__ void k_neww(const float* __restrict__ ema_w, const float* __restrict__ dw,
                       const float* __restrict__ cs_final, float* __restrict__ out) {
    int k = blockIdx.x, d = threadIdx.x;
    size_t i = (size_t)k * D_ + d;
    float ne = ema_w[i] * 0.99f + 0.01f * dw[i];
    out[O_NEW + i] = ne;
    out[O_NW + i] = ne / cs_final[k];
}

extern "C" void kernel_launch(void* const* d_in, const int* in_sizes, int n_in,
                              void* d_out, int out_size, void* d_ws, size_t ws_size,
                              hipStream_t stream) {
    (void)in_sizes; (void)n_in; (void)out_size; (void)ws_size;
    const float* x      = (const float*)d_in[0];
    const float* w      = (const float*)d_in[1];
    const float* ema_w  = (const float*)d_in[2];
    const float* ema_cs = (const float*)d_in[3];
    const float* g      = (const float*)d_in[4];
    const float* bt     = (const float*)d_in[5];
    float* out = (float*)d_out;
    char* ws = (char*)d_ws;

    float*  feats  = (float*)(ws + OFF_FEATS);
    double* A      = (double*)(ws + OFF_A);
    double* Bw     = (double*)(ws + OFF_BW);
    double* samp   = (double*)(ws + OFF_SAMP);
    int*    idxf   = (int*)(ws + OFF_IDXF);
    int*    enc    = (int*)(ws + OFF_ENC);
    float*  min1   = (float*)(ws + OFF_MIN1);
    float*  min2   = (float*)(ws + OFF_MIN2);
    int*    i1a    = (int*)(ws + OFF_I1);
    unsigned* cnt  = (unsigned*)(ws + OFF_CNT);
    float*  dw     = (float*)(ws + OFF_DW);
    double* lossA  = (double*)(ws + OFF_LOSS);
    float*  csf    = (float*)(ws + OFF_CSF);

    hipMemsetAsync(ws + ZERO_BEGIN, 0, ZERO_BYTES, stream);

    k_ln<<<N_, 64, 0, stream>>>(x, g, bt, feats, A);
    k_bw<<<K_, 64, 0, stream>>>(w, Bw);
    k_phase1<<<N_ / 64, 256, 0, stream>>>(feats, w, Bw, min1, min2, i1a);
    k_phase2<<<N_, 64, 0, stream>>>(feats, w, Bw, A, min1, min2, i1a, samp, idxf);
    k_sort<<<B_, 1024, 0, stream>>>(samp, idxf, enc);
    k_scatter<<<N_, 64, 0, stream>>>(x, w, enc, out, cnt, dw, lossA);
    k_final<<<1, 1024, 0, stream>>>(cnt, ema_cs, lossA, out, csf);
    k_neww<<<K_, 256, 0, stream>>>(ema_w, dw, csf, out);
}

// Round 2
// 514.774 us; speedup vs baseline: 2.1600x; 2.1600x over previous
//
#include <hip/hip_runtime.h>
#include <cmath>

#define B_ 32
#define S_ 1024
#define D_ 256
#define K_ 1024
#define N_ (B_*S_)

// ---- output layout (float elements) ----
#define O_Q     0
#define O_LOSS  8388608
#define O_PERP  8388609
#define O_IDX   8388610
#define O_NW    8421378
#define O_NEW   8683522
#define O_NCS   8945666

// ---- workspace layout (bytes) ----
#define OFF_FH    0ull          // N*256*2 = 16777216
#define OFF_FL    16777216ull   // 16777216
#define OFF_WH    33554432ull   // K*256*2 = 524288
#define OFF_WL    34078720ull   // 524288
#define OFF_BW    34603008ull   // K*8
#define OFF_BWF   34611200ull   // K*4
#define OFF_SAMP  34615296ull   // N*8
#define OFF_IDXF  34877440ull   // N*4
#define OFF_ENC   35008512ull   // N*4
#define OFF_MIN1  35139584ull   // N*4
#define OFF_MIN2  35270656ull   // N*4
#define OFF_I1    35401728ull   // N*4
#define OFF_CNT   35532800ull   // K*4 (zeroed)
#define OFF_LOSSP 35536896ull   // N*8
#define OFF_ROWL  35799040ull   // N*4
#define OFF_ST    35930112ull   // (K+1)*4 (reserve 4160)
#define OFF_POS   35934272ull   // K*4
#define OFF_CSF   35938368ull   // K*4

#define MARGIN 1e-4f

typedef __bf16 bf16x8 __attribute__((ext_vector_type(8)));
typedef float  f32x4  __attribute__((ext_vector_type(4)));

// ---------------- LN -> bf16 hi/lo split -------------
__global__ void k_ln(const float* __restrict__ x, const float* __restrict__ gam,
                     const float* __restrict__ bet,
                     __bf16* __restrict__ fh, __bf16* __restrict__ fl) {
    int lane = threadIdx.x & 63, wv = threadIdx.x >> 6;
    int n = blockIdx.x * 4 + wv;
    const float* row = x + (size_t)n * D_;
    double xv[4], gv[4], bv[4];
#pragma unroll
    for (int i = 0; i < 4; i++) {
        int d = lane + 64 * i;
        xv[i] = row[d]; gv[i] = gam[d]; bv[i] = bet[d];
    }
    double s = xv[0] + xv[1] + xv[2] + xv[3];
    for (int m = 32; m > 0; m >>= 1) s += __shfl_xor(s, m, 64);
    double mu = s / 256.0, vs = 0.0;
#pragma unroll
    for (int i = 0; i < 4; i++) { double c = xv[i] - mu; vs += c * c; }
    for (int m = 32; m > 0; m >>= 1) vs += __shfl_xor(vs, m, 64);
    double inv = 1.0 / sqrt(vs / 256.0 + 1e-5);
#pragma unroll
    for (int i = 0; i < 4; i++) {
        int d = lane + 64 * i;
        float ff = (float)((xv[i] - mu) * inv * gv[i] + bv[i]);
        __bf16 h = (__bf16)ff;
        fh[(size_t)n * D_ + d] = h;
        fl[(size_t)n * D_ + d] = (__bf16)(ff - (float)h);
    }
}

// ---------------- ||w||^2 (f64) + bf16 hi/lo of w -------------
__global__ void k_bw(const float* __restrict__ w, double* __restrict__ Bw,
                     float* __restrict__ Bwf,
                     __bf16* __restrict__ wh, __bf16* __restrict__ wl) {
    int lane = threadIdx.x & 63, wv = threadIdx.x >> 6;
    int k = blockIdx.x * 4 + wv;
    double s = 0.0;
#pragma unroll
    for (int i = 0; i < 4; i++) {
        int d = lane + 64 * i;
        float v = w[(size_t)k * D_ + d];
        s += (double)v * (double)v;
        __bf16 h = (__bf16)v;
        wh[(size_t)k * D_ + d] = h;
        wl[(size_t)k * D_ + d] = (__bf16)(v - (float)h);
    }
    for (int m = 32; m > 0; m >>= 1) s += __shfl_xor(s, m, 64);
    if (lane == 0) { Bw[k] = s; Bwf[k] = (float)s; }
}

// ---------------- Phase 1: bf16-split MFMA GEMM + fused top-2 -------------
// block 512 thr = 8 waves (2 row-waves x 4 col-waves); block tile 128 rows.
// code chunks of 256; Dk = 3 segments x 256 (fh*wh, fh*wl, fl*wh), BK=32.
__launch_bounds__(512, 2)
__global__ void k_phase1(const __bf16* __restrict__ fh, const __bf16* __restrict__ fl,
                         const __bf16* __restrict__ wh, const __bf16* __restrict__ wl,
                         const float* __restrict__ Bwf,
                         float* __restrict__ min1o, float* __restrict__ min2o,
                         int* __restrict__ i1o) {
    __shared__ __align__(16) __bf16 sA[2][128][40];
    __shared__ __align__(16) __bf16 sB[2][256][40];

    const int tid = threadIdx.x;
    const int lane = tid & 63;
    const int wid = tid >> 6;      // 0..7
    const int wr = wid >> 2;       // 0..1
    const int wc = wid & 3;        // 0..3
    const int l15 = lane & 15;
    const int g = lane >> 4;       // 0..3
    const int row0 = blockIdx.x * 128;

    // staging indices (same every kstep)
    const int sr  = tid >> 2;          // 0..127 (A row / B row half 1)
    const int sko = (tid & 3) * 8;     // k-offset in elements
    const int e1  = tid + 512;
    const int sr1 = e1 >> 2;           // 128..255
    const int sko1 = (e1 & 3) * 8;

    float rm1[16], rm2[16]; int rc1[16];
#pragma unroll
    for (int i = 0; i < 16; i++) { rm1[i] = 3e38f; rm2[i] = 3e38f; rc1[i] = 0x7fffffff; }

    for (int chunk = 0; chunk < 4; chunk++) {
        const int c0 = chunk * 256;
        f32x4 acc[4][4];
#pragma unroll
        for (int a = 0; a < 4; a++)
#pragma unroll
            for (int b = 0; b < 4; b++) acc[a][b] = (f32x4){0.f, 0.f, 0.f, 0.f};

        // preload kstep 0 (seg 0: fh, wh; kk=0)
        {
            uint4 ra  = *(const uint4*)(fh + (size_t)(row0 + sr) * 256 + sko);
            uint4 rb0 = *(const uint4*)(wh + (size_t)(c0 + sr) * 256 + sko);
            uint4 rb1 = *(const uint4*)(wh + (size_t)(c0 + sr1) * 256 + sko1);
            *(uint4*)&sA[0][sr][sko] = ra;
            *(uint4*)&sB[0][sr][sko] = rb0;
            *(uint4*)&sB[0][sr1][sko1] = rb1;
        }
        __syncthreads();

        for (int ks = 0; ks < 24; ks++) {
            const int cur = ks & 1, nxt = cur ^ 1;
            uint4 ra, rb0, rb1;
            const bool pf = (ks + 1 < 24);
            if (pf) {
                int k2 = ks + 1, seg = k2 >> 3, kk = k2 & 7;
                const __bf16* as = (seg == 2) ? fl : fh;
                const __bf16* bs = (seg == 1) ? wl : wh;
                ra  = *(const uint4*)(as + (size_t)(row0 + sr) * 256 + kk * 32 + sko);
                rb0 = *(const uint4*)(bs + (size_t)(c0 + sr) * 256 + kk * 32 + sko);
                rb1 = *(const uint4*)(bs + (size_t)(c0 + sr1) * 256 + kk * 32 + sko1);
            }
            bf16x8 af[4], bfr[4];
#pragma unroll
            for (int fr = 0; fr < 4; fr++)
                af[fr] = *(const bf16x8*)&sA[cur][wr * 64 + fr * 16 + l15][g * 8];
#pragma unroll
            for (int fc = 0; fc < 4; fc++)
                bfr[fc] = *(const bf16x8*)&sB[cur][wc * 64 + fc * 16 + l15][g * 8];
#pragma unroll
            for (int fr = 0; fr < 4; fr++)
#pragma unroll
                for (int fc = 0; fc < 4; fc++)
                    acc[fr][fc] = __builtin_amdgcn_mfma_f32_16x16x32_bf16(
                        af[fr], bfr[fc], acc[fr][fc], 0, 0, 0);
            __syncthreads();
            if (pf) {
                *(uint4*)&sA[nxt][sr][sko] = ra;
                *(uint4*)&sB[nxt][sr][sko] = rb0;
                *(uint4*)&sB[nxt][sr1][sko1] = rb1;
            }
            __syncthreads();
        }

        // chunk epilogue: s = Bw - 2*P, top2 per row (cols of this wave)
        float bwv[4];
#pragma unroll
        for (int fc = 0; fc < 4; fc++) bwv[fc] = Bwf[c0 + wc * 64 + fc * 16 + l15];
#pragma unroll
        for (int fr = 0; fr < 4; fr++) {
#pragma unroll
            for (int r = 0; r < 4; r++) {
                float m1 = 3e38f, m2 = 3e38f; int c1 = 0x7fffffff;
#pragma unroll
                for (int fc = 0; fc < 4; fc++) {
                    float sv = fmaf(-2.0f, acc[fr][fc][r], bwv[fc]);
                    int c = c0 + wc * 64 + fc * 16 + l15;
                    if (sv < m1 || (sv == m1 && c < c1)) { m2 = m1; m1 = sv; c1 = c; }
                    else if (sv < m2) m2 = sv;
                }
#pragma unroll
                for (int msk = 1; msk <= 8; msk <<= 1) {
                    float om1 = __shfl_xor(m1, msk, 64);
                    float om2 = __shfl_xor(m2, msk, 64);
                    int   oc  = __shfl_xor(c1, msk, 64);
                    if (om1 < m1 || (om1 == m1 && oc < c1)) {
                        m2 = (m1 < om2) ? m1 : om2; m1 = om1; c1 = oc;
                    } else {
                        m2 = (om1 < m2) ? om1 : m2;
                    }
                }
                int sl = fr * 4 + r;
                if (m1 < rm1[sl] || (m1 == rm1[sl] && c1 < rc1[sl])) {
                    rm2[sl] = (rm1[sl] < m2) ? rm1[sl] : m2; rm1[sl] = m1; rc1[sl] = c1;
                } else {
                    rm2[sl] = (m1 < rm2[sl]) ? m1 : rm2[sl];
                }
            }
        }
    }

    // cross-wave (wc) merge via LDS (reuse sB space)
    __syncthreads();
    float* red = (float*)&sB[0][0][0];   // 8*64*3 floats
    if (l15 == 0) {
#pragma unroll
        for (int fr = 0; fr < 4; fr++)
#pragma unroll
            for (int r = 0; r < 4; r++) {
                int rl = fr * 16 + g * 4 + r;
                int base = (wid * 64 + rl) * 3;
                red[base] = rm1[fr * 4 + r];
                red[base + 1] = rm2[fr * 4 + r];
                ((int*)red)[base + 2] = rc1[fr * 4 + r];
            }
    }
    __syncthreads();
    if (tid < 128) {
        int wrr = tid >> 6, rl = tid & 63;
        float M1 = 3e38f, M2 = 3e38f; int C1 = 0x7fffffff;
        for (int wcc = 0; wcc < 4; wcc++) {
            int base = ((wrr * 4 + wcc) * 64 + rl) * 3;
            float m1 = red[base], m2 = red[base + 1]; int c = ((int*)red)[base + 2];
            if (m1 < M1 || (m1 == M1 && c < C1)) {
                M2 = (M1 < m2) ? M1 : m2; M1 = m1; C1 = c;
            } else {
                M2 = (m1 < M2) ? m1 : M2;
            }
        }
        min1o[row0 + tid] = M1;
        min2o[row0 + tid] = M2;
        i1o[row0 + tid] = C1;
    }
}

// ---------------- Phase 2: exact f64 (LN recomputed) -------------
__global__ void k_phase2(const float* __restrict__ x, const float* __restrict__ gam,
                         const float* __restrict__ bet, const float* __restrict__ w,
                         const double* __restrict__ Bw,
                         const float* __restrict__ min1, const float* __restrict__ min2,
                         const int* __restrict__ i1a,
                         double* __restrict__ sampled, int* __restrict__ idxf) {
    __shared__ double sf[4][256];
    int lane = threadIdx.x & 63, wv = threadIdx.x >> 6;
    int n = blockIdx.x * 4 + wv;
    const float* row = x + (size_t)n * D_;
    double xv[4], gv[4], bv[4];
#pragma unroll
    for (int i = 0; i < 4; i++) {
        int d = lane + 64 * i;
        xv[i] = row[d]; gv[i] = gam[d]; bv[i] = bet[d];
    }
    double s = xv[0] + xv[1] + xv[2] + xv[3];
    for (int m = 32; m > 0; m >>= 1) s += __shfl_xor(s, m, 64);
    double mu = s / 256.0, vs = 0.0;
#pragma unroll
    for (int i = 0; i < 4; i++) { double c = xv[i] - mu; vs += c * c; }
    for (int m = 32; m > 0; m >>= 1) vs += __shfl_xor(vs, m, 64);
    double inv = 1.0 / sqrt(vs / 256.0 + 1e-5);
    double f[4], A = 0.0;
#pragma unroll
    for (int i = 0; i < 4; i++) {
        f[i] = (xv[i] - mu) * inv * gv[i] + bv[i];
        A += f[i] * f[i];
    }
    for (int m = 32; m > 0; m >>= 1) A += __shfl_xor(A, m, 64);

    float m1 = min1[n], m2 = min2[n]; int c1 = i1a[n];
    if (m2 - m1 > MARGIN) {
        const float* wr_ = w + (size_t)c1 * D_;
        double ss = 0.0;
#pragma unroll
        for (int i = 0; i < 4; i++) ss += f[i] * (double)wr_[lane + 64 * i];
        for (int m = 32; m > 0; m >>= 1) ss += __shfl_xor(ss, m, 64);
        if (lane == 0) { sampled[n] = (A + Bw[c1]) - 2.0 * ss; idxf[n] = c1; }
    } else {
        // rare: exact f64 scan of all codes
#pragma unroll
        for (int i = 0; i < 4; i++) sf[wv][lane + 64 * i] = f[i];
        asm volatile("s_waitcnt lgkmcnt(0)" ::: "memory");
        double bm = 1.0e300; int bc = 0x7fffffff;
        for (int c = lane; c < K_; c += 64) {
            const float* wr_ = w + (size_t)c * D_;
            double ss = 0.0;
            for (int d = 0; d < D_; d++) ss += sf[wv][d] * (double)wr_[d];
            double dist = (A + Bw[c]) - 2.0 * ss;
            if (dist < bm || (dist == bm && c < bc)) { bm = dist; bc = c; }
        }
        for (int m = 32; m > 0; m >>= 1) {
            double om = __shfl_xor(bm, m, 64);
            int    oc = __shfl_xor(bc, m, 64);
            if (om < bm || (om == bm && oc < bc)) { bm = om; bc = oc; }
        }
        if (lane == 0) { sampled[n] = bm; idxf[n] = bc; }
    }
}

// ---------------- stable argsort per batch row + enc gather -------------
__launch_bounds__(1024)
__global__ void k_sort(const double* __restrict__ sampled, const int* __restrict__ idxf,
                       int* __restrict__ enc) {
    __shared__ double val[1024];
    __shared__ int    sid[1024];
    int b = blockIdx.x, t = threadIdx.x;
    val[t] = sampled[(size_t)b * S_ + t];
    sid[t] = t;
    __syncthreads();
    for (int k = 2; k <= 1024; k <<= 1) {
        for (int j = k >> 1; j > 0; j >>= 1) {
            int p = t ^ j;
            if (p > t) {
                double v0 = val[t], v1 = val[p];
                int i0 = sid[t], i1 = sid[p];
                bool gtv = (v0 > v1) || (v0 == v1 && i0 > i1);
                bool asc = ((t & k) == 0);
                if (asc ? gtv : !gtv) {
                    val[t] = v1; val[p] = v0; sid[t] = i1; sid[p] = i0;
                }
            }
            __syncthreads();
        }
    }
    enc[(size_t)b * S_ + t] = idxf[sid[t]];   // faithful reference flat-index bug
}

// ---------------- gather: quantized out, idx out, counts, per-row loss -------------
__global__ void k_gather(const float* __restrict__ x, const float* __restrict__ w,
                         const int* __restrict__ enc, float* __restrict__ out,
                         unsigned* __restrict__ cnt, double* __restrict__ lossP) {
    int lane = threadIdx.x & 63, wv = threadIdx.x >> 6;
    int n = blockIdx.x * 4 + wv;
    int e = enc[n];
    const float* wr_ = w + (size_t)e * D_;
    const float* xr = x + (size_t)n * D_;
    float* qr = out + O_Q + (size_t)n * D_;
    double ls = 0.0;
#pragma unroll
    for (int i = 0; i < 4; i++) {
        int d = lane + 64 * i;
        float q = wr_[d], xv = xr[d];
        qr[d] = q;
        double df = (double)q - (double)xv;
        ls += df * df;
    }
    for (int m = 32; m > 0; m >>= 1) ls += __shfl_xor(ls, m, 64);
    if (lane == 0) {
        lossP[n] = ls;
        out[O_IDX + n] = (float)e;
        atomicAdd(&cnt[e], 1u);
    }
}

// ---------------- finalize: cs smoothing, loss, perplexity -------------
__launch_bounds__(1024)
__global__ void k_final(const unsigned* __restrict__ cnt, const float* __restrict__ ema_cs,
                        const double* __restrict__ lossP, float* __restrict__ out,
                        float* __restrict__ csf) {
    __shared__ double red[1024];
    int t = threadIdx.x;
    float cf = (float)cnt[t];
    float cs0 = 0.99f * ema_cs[t] + 0.01f * cf;
    red[t] = (double)cs0;
    __syncthreads();
    for (int s = 512; s > 0; s >>= 1) { if (t < s) red[t] += red[t + s]; __syncthreads(); }
    double ntot = red[0];
    __syncthreads();
    double c2 = ((double)cs0 + 1e-5) / (ntot + 1024.0 * 1e-5) * ntot;
    out[O_NCS + t] = (float)c2;
    csf[t] = (float)c2;
    double p = (double)cf / 32768.0;
    red[t] = -p * log(p + 1e-10);
    __syncthreads();
    for (int s = 512; s > 0; s >>= 1) { if (t < s) red[t] += red[t + s]; __syncthreads(); }
    double ent = red[0];
    __syncthreads();
    double ls = 0.0;
    for (int i = 0; i < 32; i++) ls += lossP[t + 1024 * i];
    red[t] = ls;
    __syncthreads();
    for (int s = 512; s > 0; s >>= 1) { if (t < s) red[t] += red[t + s]; __syncthreads(); }
    if (t == 0) {
        out[O_PERP] = (float)exp(ent);
        out[O_LOSS] = (float)(1.25 * red[0] / 8388608.0);
    }
}

// ---------------- CSR build -------------
__launch_bounds__(1024)
__global__ void k_scan(const unsigned* __restrict__ cnt, int* __restrict__ starts,
                       int* __restrict__ pos) {
    __shared__ int sc[1024];
    int t = threadIdx.x;
    int v = (int)cnt[t];
    sc[t] = v;
    __syncthreads();
    for (int off = 1; off < 1024; off <<= 1) {
        int add = (t >= off) ? sc[t - off] : 0;
        __syncthreads();
        sc[t] += add;
        __syncthreads();
    }
    int excl = sc[t] - v;
    starts[t] = excl;
    pos[t] = excl;
    if (t == 1023) starts[1024] = sc[t];
}

__global__ void k_fill(const int* __restrict__ enc, int* __restrict__ pos,
                       int* __restrict__ rowl) {
    int n = blockIdx.x * 256 + threadIdx.x;
    int p = atomicAdd(&pos[enc[n]], 1);
    rowl[p] = n;
}

// ---------------- dw gather-sum + EMA + new_weight -------------
__global__ void k_dwsum(const float* __restrict__ x, const float* __restrict__ ema_w,
                        const int* __restrict__ rowl, const int* __restrict__ starts,
                        const float* __restrict__ csf, float* __restrict__ out) {
    int k = blockIdx.x, d = threadIdx.x;
    int s0 = starts[k], s1 = starts[k + 1];
    float acc = 0.0f;
    for (int i = s0; i < s1; i++) {
        int rr = rowl[i];
        acc += x[(size_t)rr * D_ + d];
    }
    size_t idx = (size_t)k * D_ + d;
    float ne = 0.99f * ema_w[idx] + 0.01f * acc;
    out[O_NEW + idx] = ne;
    out[O_NW + idx] = ne / csf[k];
}

extern "C" void kernel_launch(void* const* d_in, const int* in_sizes, int n_in,
                              void* d_out, int out_size, void* d_ws, size_t ws_size,
                              hipStream_t stream) {
    (void)in_sizes; (void)n_in; (void)out_size; (void)ws_size;
    const float* x      = (const float*)d_in[0];
    const float* w      = (const float*)d_in[1];
    const float* ema_w  = (const float*)d_in[2];
    const float* ema_cs = (const float*)d_in[3];
    const float* g      = (const float*)d_in[4];
    const float* bt     = (const float*)d_in[5];
    float* out = (float*)d_out;
    char* ws = (char*)d_ws;

    __bf16* fh   = (__bf16*)(ws + OFF_FH);
    __bf16* fl   = (__bf16*)(ws + OFF_FL);
    __bf16* wh   = (__bf16*)(ws + OFF_WH);
    __bf16* wl   = (__bf16*)(ws + OFF_WL);
    double* Bw   = (double*)(ws + OFF_BW);
    float*  Bwf  = (float*)(ws + OFF_BWF);
    double* samp = (double*)(ws + OFF_SAMP);
    int*    idxf = (int*)(ws + OFF_IDXF);
    int*    enc  = (int*)(ws + OFF_ENC);
    float*  min1 = (float*)(ws + OFF_MIN1);
    float*  min2 = (float*)(ws + OFF_MIN2);
    int*    i1a  = (int*)(ws + OFF_I1);
    unsigned* cnt = (unsigned*)(ws + OFF_CNT);
    double* lossP = (double*)(ws + OFF_LOSSP);
    int*    rowl = (int*)(ws + OFF_ROWL);
    int*    st   = (int*)(ws + OFF_ST);
    int*    pos  = (int*)(ws + OFF_POS);
    float*  csf  = (float*)(ws + OFF_CSF);

    hipMemsetAsync(ws + OFF_CNT, 0, 4096, stream);

    k_ln<<<N_ / 4, 256, 0, stream>>>(x, g, bt, fh, fl);
    k_bw<<<K_ / 4, 256, 0, stream>>>(w, Bw, Bwf, wh, wl);
    k_phase1<<<N_ / 128, 512, 0, stream>>>(fh, fl, wh, wl, Bwf, min1, min2, i1a);
    k_phase2<<<N_ / 4, 256, 0, stream>>>(x, g, bt, w, Bw, min1, min2, i1a, samp, idxf);
    k_sort<<<B_, 1024, 0, stream>>>(samp, idxf, enc);
    k_gather<<<N_ / 4, 256, 0, stream>>>(x, w, enc, out, cnt, lossP);
    k_final<<<1, 1024, 0, stream>>>(cnt, ema_cs, lossP, out, csf);
    k_scan<<<1, 1024, 0, stream>>>(cnt, st, pos);
    k_fill<<<N_ / 256, 256, 0, stream>>>(enc, pos, rowl);
    k_dwsum<<<K_, 256, 0, stream>>>(x, ema_w, rowl, st, csf, out);
}

// Round 3
// 413.544 us; speedup vs baseline: 2.6888x; 1.2448x over previous
//
#include <hip/hip_runtime.h>
#include <cmath>

#define B_ 32
#define S_ 1024
#define D_ 256
#define K_ 1024
#define N_ (B_*S_)

// ---- output layout (float elements) ----
#define O_Q     0
#define O_LOSS  8388608
#define O_PERP  8388609
#define O_IDX   8388610
#define O_NW    8421378
#define O_NEW   8683522
#define O_NCS   8945666

// ---- workspace layout (bytes) ----
#define OFF_FH    0ull          // N*256*2 = 16777216
#define OFF_FL    16777216ull   // 16777216
#define OFF_WH    33554432ull   // K*256*2 = 524288
#define OFF_WL    34078720ull   // 524288
#define OFF_BW    34603008ull   // K*8
#define OFF_BWF   34611200ull   // K*4
#define OFF_SAMP  34615296ull   // N*8
#define OFF_IDXF  34877440ull   // N*4
#define OFF_ENC   35008512ull   // N*4
#define OFF_MIN1  35139584ull   // N*4
#define OFF_MIN2  35270656ull   // N*4
#define OFF_I1    35401728ull   // N*4
#define OFF_CNT   35532800ull   // K*4 (zeroed)
#define OFF_LOSSP 35536896ull   // N*8
#define OFF_ROWL  35799040ull   // N*4
#define OFF_ST    35930112ull   // (K+1)*4 (reserve 4160)
#define OFF_POS   35934272ull   // K*4
#define OFF_CSF   35938368ull   // K*4
#define OFF_SLOWC 35942464ull   // 4 (zeroed)
#define OFF_SLOWL 35942528ull   // N*4

#define MARGIN 4e-5f

typedef __bf16 bf16x8 __attribute__((ext_vector_type(8)));
typedef float  f32x4  __attribute__((ext_vector_type(4)));

// ---------------- LN -> bf16 hi/lo split -------------
__global__ void k_ln(const float* __restrict__ x, const float* __restrict__ gam,
                     const float* __restrict__ bet,
                     __bf16* __restrict__ fh, __bf16* __restrict__ fl) {
    int lane = threadIdx.x & 63, wv = threadIdx.x >> 6;
    int n = blockIdx.x * 4 + wv;
    const float* row = x + (size_t)n * D_;
    double xv[4], gv[4], bv[4];
#pragma unroll
    for (int i = 0; i < 4; i++) {
        int d = lane + 64 * i;
        xv[i] = row[d]; gv[i] = gam[d]; bv[i] = bet[d];
    }
    double s = xv[0] + xv[1] + xv[2] + xv[3];
    for (int m = 32; m > 0; m >>= 1) s += __shfl_xor(s, m, 64);
    double mu = s / 256.0, vs = 0.0;
#pragma unroll
    for (int i = 0; i < 4; i++) { double c = xv[i] - mu; vs += c * c; }
    for (int m = 32; m > 0; m >>= 1) vs += __shfl_xor(vs, m, 64);
    double inv = 1.0 / sqrt(vs / 256.0 + 1e-5);
#pragma unroll
    for (int i = 0; i < 4; i++) {
        int d = lane + 64 * i;
        float ff = (float)((xv[i] - mu) * inv * gv[i] + bv[i]);
        __bf16 h = (__bf16)ff;
        fh[(size_t)n * D_ + d] = h;
        fl[(size_t)n * D_ + d] = (__bf16)(ff - (float)h);
    }
}

// ---------------- ||w||^2 (f64) + bf16 hi/lo of w -------------
__global__ void k_bw(const float* __restrict__ w, double* __restrict__ Bw,
                     float* __restrict__ Bwf,
                     __bf16* __restrict__ wh, __bf16* __restrict__ wl) {
    int lane = threadIdx.x & 63, wv = threadIdx.x >> 6;
    int k = blockIdx.x * 4 + wv;
    double s = 0.0;
#pragma unroll
    for (int i = 0; i < 4; i++) {
        int d = lane + 64 * i;
        float v = w[(size_t)k * D_ + d];
        s += (double)v * (double)v;
        __bf16 h = (__bf16)v;
        wh[(size_t)k * D_ + d] = h;
        wl[(size_t)k * D_ + d] = (__bf16)(v - (float)h);
    }
    for (int m = 32; m > 0; m >>= 1) s += __shfl_xor(s, m, 64);
    if (lane == 0) { Bw[k] = s; Bwf[k] = (float)s; }
}

// ---------------- Phase 1: bf16-split MFMA GEMM + fused top-2 -------------
__launch_bounds__(512, 2)
__global__ void k_phase1(const __bf16* __restrict__ fh, const __bf16* __restrict__ fl,
                         const __bf16* __restrict__ wh, const __bf16* __restrict__ wl,
                         const float* __restrict__ Bwf,
                         float* __restrict__ min1o, float* __restrict__ min2o,
                         int* __restrict__ i1o) {
    __shared__ __align__(16) __bf16 sA[2][128][40];
    __shared__ __align__(16) __bf16 sB[2][256][40];

    const int tid = threadIdx.x;
    const int lane = tid & 63;
    const int wid = tid >> 6;      // 0..7
    const int wr = wid >> 2;       // 0..1
    const int wc = wid & 3;        // 0..3
    const int l15 = lane & 15;
    const int g = lane >> 4;       // 0..3
    const int row0 = blockIdx.x * 128;

    const int sr  = tid >> 2;
    const int sko = (tid & 3) * 8;
    const int e1  = tid + 512;
    const int sr1 = e1 >> 2;
    const int sko1 = (e1 & 3) * 8;

    float rm1[16], rm2[16]; int rc1[16];
#pragma unroll
    for (int i = 0; i < 16; i++) { rm1[i] = 3e38f; rm2[i] = 3e38f; rc1[i] = 0x7fffffff; }

    for (int chunk = 0; chunk < 4; chunk++) {
        const int c0 = chunk * 256;
        f32x4 acc[4][4];
#pragma unroll
        for (int a = 0; a < 4; a++)
#pragma unroll
            for (int b = 0; b < 4; b++) acc[a][b] = (f32x4){0.f, 0.f, 0.f, 0.f};

        {
            uint4 ra  = *(const uint4*)(fh + (size_t)(row0 + sr) * 256 + sko);
            uint4 rb0 = *(const uint4*)(wh + (size_t)(c0 + sr) * 256 + sko);
            uint4 rb1 = *(const uint4*)(wh + (size_t)(c0 + sr1) * 256 + sko1);
            *(uint4*)&sA[0][sr][sko] = ra;
            *(uint4*)&sB[0][sr][sko] = rb0;
            *(uint4*)&sB[0][sr1][sko1] = rb1;
        }
        __syncthreads();

        for (int ks = 0; ks < 24; ks++) {
            const int cur = ks & 1, nxt = cur ^ 1;
            uint4 ra, rb0, rb1;
            const bool pf = (ks + 1 < 24);
            if (pf) {
                int k2 = ks + 1, seg = k2 >> 3, kk = k2 & 7;
                const __bf16* as = (seg == 2) ? fl : fh;
                const __bf16* bs = (seg == 1) ? wl : wh;
                ra  = *(const uint4*)(as + (size_t)(row0 + sr) * 256 + kk * 32 + sko);
                rb0 = *(const uint4*)(bs + (size_t)(c0 + sr) * 256 + kk * 32 + sko);
                rb1 = *(const uint4*)(bs + (size_t)(c0 + sr1) * 256 + kk * 32 + sko1);
            }
            bf16x8 af[4], bfr[4];
#pragma unroll
            for (int fr = 0; fr < 4; fr++)
                af[fr] = *(const bf16x8*)&sA[cur][wr * 64 + fr * 16 + l15][g * 8];
#pragma unroll
            for (int fc = 0; fc < 4; fc++)
                bfr[fc] = *(const bf16x8*)&sB[cur][wc * 64 + fc * 16 + l15][g * 8];
#pragma unroll
            for (int fr = 0; fr < 4; fr++)
#pragma unroll
                for (int fc = 0; fc < 4; fc++)
                    acc[fr][fc] = __builtin_amdgcn_mfma_f32_16x16x32_bf16(
                        af[fr], bfr[fc], acc[fr][fc], 0, 0, 0);
            __syncthreads();
            if (pf) {
                *(uint4*)&sA[nxt][sr][sko] = ra;
                *(uint4*)&sB[nxt][sr][sko] = rb0;
                *(uint4*)&sB[nxt][sr1][sko1] = rb1;
            }
            __syncthreads();
        }

        float bwv[4];
#pragma unroll
        for (int fc = 0; fc < 4; fc++) bwv[fc] = Bwf[c0 + wc * 64 + fc * 16 + l15];
#pragma unroll
        for (int fr = 0; fr < 4; fr++) {
#pragma unroll
            for (int r = 0; r < 4; r++) {
                float m1 = 3e38f, m2 = 3e38f; int c1 = 0x7fffffff;
#pragma unroll
                for (int fc = 0; fc < 4; fc++) {
                    float sv = fmaf(-2.0f, acc[fr][fc][r], bwv[fc]);
                    int c = c0 + wc * 64 + fc * 16 + l15;
                    if (sv < m1 || (sv == m1 && c < c1)) { m2 = m1; m1 = sv; c1 = c; }
                    else if (sv < m2) m2 = sv;
                }
#pragma unroll
                for (int msk = 1; msk <= 8; msk <<= 1) {
                    float om1 = __shfl_xor(m1, msk, 64);
                    float om2 = __shfl_xor(m2, msk, 64);
                    int   oc  = __shfl_xor(c1, msk, 64);
                    if (om1 < m1 || (om1 == m1 && oc < c1)) {
                        m2 = (m1 < om2) ? m1 : om2; m1 = om1; c1 = oc;
                    } else {
                        m2 = (om1 < m2) ? om1 : m2;
                    }
                }
                int sl = fr * 4 + r;
                if (m1 < rm1[sl] || (m1 == rm1[sl] && c1 < rc1[sl])) {
                    rm2[sl] = (rm1[sl] < m2) ? rm1[sl] : m2; rm1[sl] = m1; rc1[sl] = c1;
                } else {
                    rm2[sl] = (m1 < rm2[sl]) ? m1 : rm2[sl];
                }
            }
        }
    }

    __syncthreads();
    float* red = (float*)&sB[0][0][0];
    if (l15 == 0) {
#pragma unroll
        for (int fr = 0; fr < 4; fr++)
#pragma unroll
            for (int r = 0; r < 4; r++) {
                int rl = fr * 16 + g * 4 + r;
                int base = (wid * 64 + rl) * 3;
                red[base] = rm1[fr * 4 + r];
                red[base + 1] = rm2[fr * 4 + r];
                ((int*)red)[base + 2] = rc1[fr * 4 + r];
            }
    }
    __syncthreads();
    if (tid < 128) {
        int wrr = tid >> 6, rl = tid & 63;
        float M1 = 3e38f, M2 = 3e38f; int C1 = 0x7fffffff;
        for (int wcc = 0; wcc < 4; wcc++) {
            int base = ((wrr * 4 + wcc) * 64 + rl) * 3;
            float m1 = red[base], m2 = red[base + 1]; int c = ((int*)red)[base + 2];
            if (m1 < M1 || (m1 == M1 && c < C1)) {
                M2 = (M1 < m2) ? M1 : m2; M1 = m1; C1 = c;
            } else {
                M2 = (m1 < M2) ? m1 : M2;
            }
        }
        min1o[row0 + tid] = M1;
        min2o[row0 + tid] = M2;
        i1o[row0 + tid] = C1;
    }
}

// ---------------- Phase 2 (fast): exact f64 verify of winner; append slow rows ----
__global__ void k_phase2(const float* __restrict__ x, const float* __restrict__ gam,
                         const float* __restrict__ bet, const float* __restrict__ w,
                         const double* __restrict__ Bw,
                         const float* __restrict__ min1, const float* __restrict__ min2,
                         const int* __restrict__ i1a,
                         double* __restrict__ sampled, int* __restrict__ idxf,
                         unsigned* __restrict__ slowC, int* __restrict__ slowL) {
    int lane = threadIdx.x & 63, wv = threadIdx.x >> 6;
    int n = blockIdx.x * 4 + wv;
    float m1 = min1[n], m2 = min2[n]; int c1 = i1a[n];
    if (m2 - m1 <= MARGIN) {
        if (lane == 0) {
            unsigned p = atomicAdd(slowC, 1u);
            slowL[p] = n;
        }
        return;
    }
    const float* row = x + (size_t)n * D_;
    double xv[4], gv[4], bv[4];
#pragma unroll
    for (int i = 0; i < 4; i++) {
        int d = lane + 64 * i;
        xv[i] = row[d]; gv[i] = gam[d]; bv[i] = bet[d];
    }
    double s = xv[0] + xv[1] + xv[2] + xv[3];
    for (int m = 32; m > 0; m >>= 1) s += __shfl_xor(s, m, 64);
    double mu = s / 256.0, vs = 0.0;
#pragma unroll
    for (int i = 0; i < 4; i++) { double c = xv[i] - mu; vs += c * c; }
    for (int m = 32; m > 0; m >>= 1) vs += __shfl_xor(vs, m, 64);
    double inv = 1.0 / sqrt(vs / 256.0 + 1e-5);
    double f[4], A = 0.0;
#pragma unroll
    for (int i = 0; i < 4; i++) {
        f[i] = (xv[i] - mu) * inv * gv[i] + bv[i];
        A += f[i] * f[i];
    }
    for (int m = 32; m > 0; m >>= 1) A += __shfl_xor(A, m, 64);

    const float* wr_ = w + (size_t)c1 * D_;
    double ss = 0.0;
#pragma unroll
    for (int i = 0; i < 4; i++) ss += f[i] * (double)wr_[lane + 64 * i];
    for (int m = 32; m > 0; m >>= 1) ss += __shfl_xor(ss, m, 64);
    if (lane == 0) { sampled[n] = (A + Bw[c1]) - 2.0 * ss; idxf[n] = c1; }
}

// ---------------- Slow rows: compacted exact f64 full scan -------------
// block per row; wave wv scans codes [wv*256, wv*256+256); lanes over dims (float4)
__launch_bounds__(256)
__global__ void k_slow(const float* __restrict__ x, const float* __restrict__ gam,
                       const float* __restrict__ bet, const float* __restrict__ w,
                       const double* __restrict__ Bw,
                       const int* __restrict__ slowL, const unsigned* __restrict__ slowC,
                       double* __restrict__ sampled, int* __restrict__ idxf) {
    __shared__ double bmS[4];
    __shared__ int    bcS[4];
    int lane = threadIdx.x & 63, wv = threadIdx.x >> 6;
    int cnt = (int)*slowC;
    for (int it = blockIdx.x; it < cnt; it += gridDim.x) {
        int n = slowL[it];
        const float* row = x + (size_t)n * D_;
        float4 xv4 = *(const float4*)(row + lane * 4);
        float4 gv4 = *(const float4*)(gam + lane * 4);
        float4 bv4 = *(const float4*)(bet + lane * 4);
        double xv[4] = {(double)xv4.x, (double)xv4.y, (double)xv4.z, (double)xv4.w};
        double gv[4] = {(double)gv4.x, (double)gv4.y, (double)gv4.z, (double)gv4.w};
        double bv[4] = {(double)bv4.x, (double)bv4.y, (double)bv4.z, (double)bv4.w};
        double s = xv[0] + xv[1] + xv[2] + xv[3];
        for (int m = 32; m > 0; m >>= 1) s += __shfl_xor(s, m, 64);
        double mu = s / 256.0, vs = 0.0;
#pragma unroll
        for (int i = 0; i < 4; i++) { double c = xv[i] - mu; vs += c * c; }
        for (int m = 32; m > 0; m >>= 1) vs += __shfl_xor(vs, m, 64);
        double inv = 1.0 / sqrt(vs / 256.0 + 1e-5);
        double f[4], A = 0.0;
#pragma unroll
        for (int i = 0; i < 4; i++) {
            f[i] = (xv[i] - mu) * inv * gv[i] + bv[i];
            A += f[i] * f[i];
        }
        for (int m = 32; m > 0; m >>= 1) A += __shfl_xor(A, m, 64);

        double bm = 1.0e300; int bc = 0x7fffffff;
        int cbase = wv * 256;
#pragma unroll 2
        for (int c = cbase; c < cbase + 256; c++) {
            float4 w4 = *(const float4*)(w + (size_t)c * D_ + lane * 4);
            double ss = f[0] * (double)w4.x + f[1] * (double)w4.y
                      + f[2] * (double)w4.z + f[3] * (double)w4.w;
            for (int m = 32; m > 0; m >>= 1) ss += __shfl_xor(ss, m, 64);
            double dist = (A + Bw[c]) - 2.0 * ss;
            if (dist < bm) { bm = dist; bc = c; }  // ascending c => lowest idx on tie
        }
        if (lane == 0) { bmS[wv] = bm; bcS[wv] = bc; }
        __syncthreads();
        if (threadIdx.x == 0) {
            double M = bmS[0]; int C = bcS[0];
            for (int i = 1; i < 4; i++)
                if (bmS[i] < M || (bmS[i] == M && bcS[i] < C)) { M = bmS[i]; C = bcS[i]; }
            sampled[n] = M; idxf[n] = C;
        }
        __syncthreads();
    }
}

// ---------------- stable argsort per batch row + enc gather -------------
__launch_bounds__(1024)
__global__ void k_sort(const double* __restrict__ sampled, const int* __restrict__ idxf,
                       int* __restrict__ enc) {
    __shared__ double val[1024];
    __shared__ int    sid[1024];
    int b = blockIdx.x, t = threadIdx.x;
    val[t] = sampled[(size_t)b * S_ + t];
    sid[t] = t;
    __syncthreads();
    for (int k = 2; k <= 1024; k <<= 1) {
        for (int j = k >> 1; j > 0; j >>= 1) {
            int p = t ^ j;
            if (p > t) {
                double v0 = val[t], v1 = val[p];
                int i0 = sid[t], i1 = sid[p];
                bool gtv = (v0 > v1) || (v0 == v1 && i0 > i1);
                bool asc = ((t & k) == 0);
                if (asc ? gtv : !gtv) {
                    val[t] = v1; val[p] = v0; sid[t] = i1; sid[p] = i0;
                }
            }
            __syncthreads();
        }
    }
    enc[(size_t)b * S_ + t] = idxf[sid[t]];   // faithful reference flat-index bug
}

// ---------------- gather: quantized out, idx out, counts, per-row loss -------------
__global__ void k_gather(const float* __restrict__ x, const float* __restrict__ w,
                         const int* __restrict__ enc, float* __restrict__ out,
                         unsigned* __restrict__ cnt, double* __restrict__ lossP) {
    int lane = threadIdx.x & 63, wv = threadIdx.x >> 6;
    int n = blockIdx.x * 4 + wv;
    int e = enc[n];
    const float* wr_ = w + (size_t)e * D_;
    const float* xr = x + (size_t)n * D_;
    float* qr = out + O_Q + (size_t)n * D_;
    double ls = 0.0;
#pragma unroll
    for (int i = 0; i < 4; i++) {
        int d = lane + 64 * i;
        float q = wr_[d], xv = xr[d];
        qr[d] = q;
        double df = (double)q - (double)xv;
        ls += df * df;
    }
    for (int m = 32; m > 0; m >>= 1) ls += __shfl_xor(ls, m, 64);
    if (lane == 0) {
        lossP[n] = ls;
        out[O_IDX + n] = (float)e;
        atomicAdd(&cnt[e], 1u);
    }
}

// ---------------- finalize: cs smoothing, loss, perplexity -------------
__launch_bounds__(1024)
__global__ void k_final(const unsigned* __restrict__ cnt, const float* __restrict__ ema_cs,
                        const double* __restrict__ lossP, float* __restrict__ out,
                        float* __restrict__ csf) {
    __shared__ double red[1024];
    int t = threadIdx.x;
    float cf = (float)cnt[t];
    float cs0 = 0.99f * ema_cs[t] + 0.01f * cf;
    red[t] = (double)cs0;
    __syncthreads();
    for (int s = 512; s > 0; s >>= 1) { if (t < s) red[t] += red[t + s]; __syncthreads(); }
    double ntot = red[0];
    __syncthreads();
    double c2 = ((double)cs0 + 1e-5) / (ntot + 1024.0 * 1e-5) * ntot;
    out[O_NCS + t] = (float)c2;
    csf[t] = (float)c2;
    double p = (double)cf / 32768.0;
    red[t] = -p * log(p + 1e-10);
    __syncthreads();
    for (int s = 512; s > 0; s >>= 1) { if (t < s) red[t] += red[t + s]; __syncthreads(); }
    double ent = red[0];
    __syncthreads();
    double ls = 0.0;
    for (int i = 0; i < 32; i++) ls += lossP[t + 1024 * i];
    red[t] = ls;
    __syncthreads();
    for (int s = 512; s > 0; s >>= 1) { if (t < s) red[t] += red[t + s]; __syncthreads(); }
    if (t == 0) {
        out[O_PERP] = (float)exp(ent);
        out[O_LOSS] = (float)(1.25 * red[0] / 8388608.0);
    }
}

// ---------------- CSR build -------------
__launch_bounds__(1024)
__global__ void k_scan(const unsigned* __restrict__ cnt, int* __restrict__ starts,
                       int* __restrict__ pos) {
    __shared__ int sc[1024];
    int t = threadIdx.x;
    int v = (int)cnt[t];
    sc[t] = v;
    __syncthreads();
    for (int off = 1; off < 1024; off <<= 1) {
        int add = (t >= off) ? sc[t - off] : 0;
        __syncthreads();
        sc[t] += add;
        __syncthreads();
    }
    int excl = sc[t] - v;
    starts[t] = excl;
    pos[t] = excl;
    if (t == 1023) starts[1024] = sc[t];
}

__global__ void k_fill(const int* __restrict__ enc, int* __restrict__ pos,
                       int* __restrict__ rowl) {
    int n = blockIdx.x * 256 + threadIdx.x;
    int p = atomicAdd(&pos[enc[n]], 1);
    rowl[p] = n;
}

// ---------------- dw gather-sum + EMA + new_weight -------------
__global__ void k_dwsum(const float* __restrict__ x, const float* __restrict__ ema_w,
                        const int* __restrict__ rowl, const int* __restrict__ starts,
                        const float* __restrict__ csf, float* __restrict__ out) {
    int k = blockIdx.x, d = threadIdx.x;
    int s0 = starts[k], s1 = starts[k + 1];
    float acc = 0.0f;
    for (int i = s0; i < s1; i++) {
        int rr = rowl[i];
        acc += x[(size_t)rr * D_ + d];
    }
    size_t idx = (size_t)k * D_ + d;
    float ne = 0.99f * ema_w[idx] + 0.01f * acc;
    out[O_NEW + idx] = ne;
    out[O_NW + idx] = ne / csf[k];
}

extern "C" void kernel_launch(void* const* d_in, const int* in_sizes, int n_in,
                              void* d_out, int out_size, void* d_ws, size_t ws_size,
                              hipStream_t stream) {
    (void)in_sizes; (void)n_in; (void)out_size; (void)ws_size;
    const float* x      = (const float*)d_in[0];
    const float* w      = (const float*)d_in[1];
    const float* ema_w  = (const float*)d_in[2];
    const float* ema_cs = (const float*)d_in[3];
    const float* g      = (const float*)d_in[4];
    const float* bt     = (const float*)d_in[5];
    float* out = (float*)d_out;
    char* ws = (char*)d_ws;

    __bf16* fh   = (__bf16*)(ws + OFF_FH);
    __bf16* fl   = (__bf16*)(ws + OFF_FL);
    __bf16* wh   = (__bf16*)(ws + OFF_WH);
    __bf16* wl   = (__bf16*)(ws + OFF_WL);
    double* Bw   = (double*)(ws + OFF_BW);
    float*  Bwf  = (float*)(ws + OFF_BWF);
    double* samp = (double*)(ws + OFF_SAMP);
    int*    idxf = (int*)(ws + OFF_IDXF);
    int*    enc  = (int*)(ws + OFF_ENC);
    float*  min1 = (float*)(ws + OFF_MIN1);
    float*  min2 = (float*)(ws + OFF_MIN2);
    int*    i1a  = (int*)(ws + OFF_I1);
    unsigned* cnt = (unsigned*)(ws + OFF_CNT);
    double* lossP = (double*)(ws + OFF_LOSSP);
    int*    rowl = (int*)(ws + OFF_ROWL);
    int*    st   = (int*)(ws + OFF_ST);
    int*    pos  = (int*)(ws + OFF_POS);
    float*  csf  = (float*)(ws + OFF_CSF);
    unsigned* slowC = (unsigned*)(ws + OFF_SLOWC);
    int*    slowL = (int*)(ws + OFF_SLOWL);

    hipMemsetAsync(ws + OFF_CNT, 0, 4096, stream);
    hipMemsetAsync(ws + OFF_SLOWC, 0, 64, stream);

    k_ln<<<N_ / 4, 256, 0, stream>>>(x, g, bt, fh, fl);
    k_bw<<<K_ / 4, 256, 0, stream>>>(w, Bw, Bwf, wh, wl);
    k_phase1<<<N_ / 128, 512, 0, stream>>>(fh, fl, wh, wl, Bwf, min1, min2, i1a);
    k_phase2<<<N_ / 4, 256, 0, stream>>>(x, g, bt, w, Bw, min1, min2, i1a, samp, idxf,
                                         slowC, slowL);
    k_slow<<<1024, 256, 0, stream>>>(x, g, bt, w, Bw, slowL, slowC, samp, idxf);
    k_sort<<<B_, 1024, 0, stream>>>(samp, idxf, enc);
    k_gather<<<N_ / 4, 256, 0, stream>>>(x, w, enc, out, cnt, lossP);
    k_final<<<1, 1024, 0, stream>>>(cnt, ema_cs, lossP, out, csf);
    k_scan<<<1, 1024, 0, stream>>>(cnt, st, pos);
    k_fill<<<N_ / 256, 256, 0, stream>>>(enc, pos, rowl);
    k_dwsum<<<K_, 256, 0, stream>>>(x, ema_w, rowl, st, csf, out);
}

// Round 5
// 405.859 us; speedup vs baseline: 2.7397x; 1.0189x over previous
//
#include <hip/hip_runtime.h>
#include <cmath>

#define B_ 32
#define S_ 1024
#define D_ 256
#define K_ 1024
#define N_ (B_*S_)

// ---- output layout (float elements) ----
#define O_Q     0
#define O_LOSS  8388608
#define O_PERP  8388609
#define O_IDX   8388610
#define O_NW    8421378
#define O_NEW   8683522
#define O_NCS   8945666

// ---- workspace layout (bytes) ----
#define OFF_FH    0ull          // 16777216
#define OFF_FL    16777216ull   // 16777216
#define OFF_WH    33554432ull   // 524288
#define OFF_WL    34078720ull   // 524288
#define OFF_BW    34603008ull   // K*8
#define OFF_BWF   34611200ull   // K*4
#define OFF_SAMP  34615296ull   // N*8
#define OFF_IDXF  34877440ull   // N*4
#define OFF_ENC   35008512ull   // N*4
#define OFF_CNT   35139584ull   // K*4   (zeroed)
#define OFF_SLOWC 35143680ull   // 64    (zeroed, same memset)
#define OFF_SLOWL 35143744ull   // N*4
#define OFF_LOSSP 35274816ull   // N*8
#define OFF_ROWL  35536960ull   // N*4
#define OFF_ST    35668032ull   // (K+1)*4
#define OFF_POS   35672192ull   // K*4
#define OFF_CSF   35676288ull   // K*4

#define MARGIN 1e-5f

typedef __bf16 bf16x8 __attribute__((ext_vector_type(8)));
typedef float  f32x4  __attribute__((ext_vector_type(4)));

// offset arg must be a literal at Sema time -> fold k-offset into gp instead.
#define GL16(gp, lp) __builtin_amdgcn_global_load_lds( \
    (const __attribute__((address_space(1))) unsigned int*)(const void*)(gp), \
    (__attribute__((address_space(3))) unsigned int*)(void*)(lp), 16, 0, 0)

// ---------------- LN -> bf16 hi/lo split -------------
__global__ void k_ln(const float* __restrict__ x, const float* __restrict__ gam,
                     const float* __restrict__ bet,
                     __bf16* __restrict__ fh, __bf16* __restrict__ fl) {
    int lane = threadIdx.x & 63, wv = threadIdx.x >> 6;
    int n = blockIdx.x * 4 + wv;
    const float* row = x + (size_t)n * D_;
    double xv[4], gv[4], bv[4];
#pragma unroll
    for (int i = 0; i < 4; i++) {
        int d = lane + 64 * i;
        xv[i] = row[d]; gv[i] = gam[d]; bv[i] = bet[d];
    }
    double s = xv[0] + xv[1] + xv[2] + xv[3];
    for (int m = 32; m > 0; m >>= 1) s += __shfl_xor(s, m, 64);
    double mu = s / 256.0, vs = 0.0;
#pragma unroll
    for (int i = 0; i < 4; i++) { double c = xv[i] - mu; vs += c * c; }
    for (int m = 32; m > 0; m >>= 1) vs += __shfl_xor(vs, m, 64);
    double inv = 1.0 / sqrt(vs / 256.0 + 1e-5);
#pragma unroll
    for (int i = 0; i < 4; i++) {
        int d = lane + 64 * i;
        float ff = (float)((xv[i] - mu) * inv * gv[i] + bv[i]);
        __bf16 h = (__bf16)ff;
        fh[(size_t)n * D_ + d] = h;
        fl[(size_t)n * D_ + d] = (__bf16)(ff - (float)h);
    }
}

// ---------------- ||w||^2 (f64) + bf16 hi/lo of w -------------
__global__ void k_bw(const float* __restrict__ w, double* __restrict__ Bw,
                     float* __restrict__ Bwf,
                     __bf16* __restrict__ wh, __bf16* __restrict__ wl) {
    int lane = threadIdx.x & 63, wv = threadIdx.x >> 6;
    int k = blockIdx.x * 4 + wv;
    double s = 0.0;
#pragma unroll
    for (int i = 0; i < 4; i++) {
        int d = lane + 64 * i;
        float v = w[(size_t)k * D_ + d];
        s += (double)v * (double)v;
        __bf16 h = (__bf16)v;
        wh[(size_t)k * D_ + d] = h;
        wl[(size_t)k * D_ + d] = (__bf16)(v - (float)h);
    }
    for (int m = 32; m > 0; m >>= 1) s += __shfl_xor(s, m, 64);
    if (lane == 0) { Bw[k] = s; Bwf[k] = (float)s; }
}

// ---------------- Phase 1: bf16-split MFMA GEMM + fused top-2 -------------
// 2048 blocks x 256 thr. Block = 64 rows x 256 codes (chunk = blockIdx&3).
// Wave w: 64 rows x codes [w*64, w*64+64). K = 3 segs x 256 (fh*wh, fh*wl, fl*wh).
// global_load_lds dwordx4 staging into packed double-buffered LDS.
__launch_bounds__(256, 4)
__global__ void k_phase1(const __bf16* __restrict__ fh, const __bf16* __restrict__ fl,
                         const __bf16* __restrict__ wh, const __bf16* __restrict__ wl,
                         const float* __restrict__ Bwf, float* __restrict__ pq) {
    __shared__ __align__(16) __bf16 sA[2][64][32];
    __shared__ __align__(16) __bf16 sB[2][256][32];

    const int tid = threadIdx.x;
    const int lane = tid & 63;
    const int w = tid >> 6;        // wave 0..3
    const int l15 = lane & 15;
    const int g = lane >> 4;       // 0..3
    const int chunk = blockIdx.x & 3;
    const int row0 = (blockIdx.x >> 2) * 64;
    const int c0 = chunk * 256;

    // staging: lane l -> LDS offset l*16B => row base+(l>>2), col (l&3)*8
    const int srow = lane >> 2;
    const int scol = (lane & 3) * 8;
    const __bf16* gafh = fh + (size_t)(row0 + w * 16 + srow) * 256 + scol;
    const __bf16* gafl = fl + (size_t)(row0 + w * 16 + srow) * 256 + scol;
    const __bf16* gbwh = wh + (size_t)(c0 + w * 64 + srow) * 256 + scol;
    const __bf16* gbwl = wl + (size_t)(c0 + w * 64 + srow) * 256 + scol;

    f32x4 acc[4][4];
#pragma unroll
    for (int a = 0; a < 4; a++)
#pragma unroll
        for (int b = 0; b < 4; b++) acc[a][b] = (f32x4){0.f, 0.f, 0.f, 0.f};

    // preload ks=0 (seg 0: fh x wh, kk=0)
    GL16(gafh, &sA[0][w * 16][0]);
    GL16(gbwh,         &sB[0][w * 64][0]);
    GL16(gbwh + 4096,  &sB[0][w * 64 + 16][0]);
    GL16(gbwh + 8192,  &sB[0][w * 64 + 32][0]);
    GL16(gbwh + 12288, &sB[0][w * 64 + 48][0]);

#pragma unroll
    for (int ks = 0; ks < 24; ks++) {
        __syncthreads();   // barrier drain => buf[cur] staging complete
        if (ks < 23) {
            const int k2 = ks + 1;
            const int buf = k2 & 1;
            const int eoff = (k2 & 7) * 32;   // element offset within segment row
            const __bf16* ga = ((k2 >= 16) ? gafl : gafh) + eoff;
            const __bf16* gb = ((k2 >= 8 && k2 < 16) ? gbwl : gbwh) + eoff;
            GL16(ga, &sA[buf][w * 16][0]);
            GL16(gb,         &sB[buf][w * 64][0]);
            GL16(gb + 4096,  &sB[buf][w * 64 + 16][0]);
            GL16(gb + 8192,  &sB[buf][w * 64 + 32][0]);
            GL16(gb + 12288, &sB[buf][w * 64 + 48][0]);
        }
        const int cur = ks & 1;
        bf16x8 af[4], bfr[4];
#pragma unroll
        for (int fr = 0; fr < 4; fr++)
            af[fr] = *(const bf16x8*)&sA[cur][fr * 16 + l15][g * 8];
#pragma unroll
        for (int fc = 0; fc < 4; fc++)
            bfr[fc] = *(const bf16x8*)&sB[cur][w * 64 + fc * 16 + l15][g * 8];
#pragma unroll
        for (int fr = 0; fr < 4; fr++)
#pragma unroll
            for (int fc = 0; fc < 4; fc++)
                acc[fr][fc] = __builtin_amdgcn_mfma_f32_16x16x32_bf16(
                    af[fr], bfr[fc], acc[fr][fc], 0, 0, 0);
    }
    __syncthreads();

    // epilogue: s = Bw - 2P, top-2 per row over this wave's 64 codes
    float bwv[4];
#pragma unroll
    for (int fc = 0; fc < 4; fc++) bwv[fc] = Bwf[c0 + w * 64 + fc * 16 + l15];
    float* red = (float*)&sB[0][0][0];   // 4 waves x 64 rows x 3
#pragma unroll
    for (int fr = 0; fr < 4; fr++) {
#pragma unroll
        for (int r = 0; r < 4; r++) {
            float m1 = 3e38f, m2 = 3e38f; int c1 = 0x7fffffff;
#pragma unroll
            for (int fc = 0; fc < 4; fc++) {
                float sv = fmaf(-2.0f, acc[fr][fc][r], bwv[fc]);
                int c = c0 + w * 64 + fc * 16 + l15;
                if (sv < m1 || (sv == m1 && c < c1)) { m2 = m1; m1 = sv; c1 = c; }
                else if (sv < m2) m2 = sv;
            }
#pragma unroll
            for (int msk = 1; msk <= 8; msk <<= 1) {
                float om1 = __shfl_xor(m1, msk, 64);
                float om2 = __shfl_xor(m2, msk, 64);
                int   oc  = __shfl_xor(c1, msk, 64);
                if (om1 < m1 || (om1 == m1 && oc < c1)) {
                    m2 = (m1 < om2) ? m1 : om2; m1 = om1; c1 = oc;
                } else {
                    m2 = (om1 < m2) ? om1 : m2;
                }
            }
            if (l15 == 0) {
                int rl = fr * 16 + g * 4 + r;
                int base = (w * 64 + rl) * 3;
                red[base] = m1; red[base + 1] = m2; ((int*)red)[base + 2] = c1;
            }
        }
    }
    __syncthreads();
    if (tid < 64) {
        float M1 = 3e38f, M2 = 3e38f; int C1 = 0x7fffffff;
        for (int wv = 0; wv < 4; wv++) {   // ascending code order => tie-break OK
            int base = (wv * 64 + tid) * 3;
            float m1 = red[base], m2 = red[base + 1]; int c = ((int*)red)[base + 2];
            if (m1 < M1 || (m1 == M1 && c < C1)) {
                M2 = (M1 < m2) ? M1 : m2; M1 = m1; C1 = c;
            } else {
                M2 = (m1 < M2) ? m1 : M2;
            }
        }
        pq[chunk * N_ + row0 + tid] = M1;                    // pm1
        pq[4 * N_ + chunk * N_ + row0 + tid] = M2;           // pm2
        ((int*)pq)[8 * N_ + chunk * N_ + row0 + tid] = C1;   // pc1
    }
}

// ---------------- Phase 2: merge 4 chunk-partials + exact f64 verify ----
__global__ void k_phase2(const float* __restrict__ x, const float* __restrict__ gam,
                         const float* __restrict__ bet, const float* __restrict__ w,
                         const double* __restrict__ Bw, const float* __restrict__ pq,
                         double* __restrict__ sampled, int* __restrict__ idxf,
                         unsigned* __restrict__ slowC, int* __restrict__ slowL) {
    int lane = threadIdx.x & 63, wv = threadIdx.x >> 6;
    int n = blockIdx.x * 4 + wv;
    const float* pm1 = pq;
    const float* pm2 = pq + 4 * N_;
    const int*   pc1 = (const int*)pq + 8 * N_;
    float M1 = 3e38f, M2 = 3e38f; int C1 = 0x7fffffff;
#pragma unroll
    for (int c = 0; c < 4; c++) {
        float m1 = pm1[c * N_ + n], m2 = pm2[c * N_ + n]; int cc = pc1[c * N_ + n];
        if (m1 < M1 || (m1 == M1 && cc < C1)) {
            M2 = (M1 < m2) ? M1 : m2; M1 = m1; C1 = cc;
        } else {
            M2 = (m1 < M2) ? m1 : M2;
        }
    }
    if (M2 - M1 <= MARGIN) {
        if (lane == 0) { unsigned p = atomicAdd(slowC, 1u); slowL[p] = n; }
        return;
    }
    const float* row = x + (size_t)n * D_;
    double xv[4], gv[4], bv[4];
#pragma unroll
    for (int i = 0; i < 4; i++) {
        int d = lane + 64 * i;
        xv[i] = row[d]; gv[i] = gam[d]; bv[i] = bet[d];
    }
    double s = xv[0] + xv[1] + xv[2] + xv[3];
    for (int m = 32; m > 0; m >>= 1) s += __shfl_xor(s, m, 64);
    double mu = s / 256.0, vs = 0.0;
#pragma unroll
    for (int i = 0; i < 4; i++) { double c = xv[i] - mu; vs += c * c; }
    for (int m = 32; m > 0; m >>= 1) vs += __shfl_xor(vs, m, 64);
    double inv = 1.0 / sqrt(vs / 256.0 + 1e-5);
    double f[4], A = 0.0;
#pragma unroll
    for (int i = 0; i < 4; i++) {
        f[i] = (xv[i] - mu) * inv * gv[i] + bv[i];
        A += f[i] * f[i];
    }
    for (int m = 32; m > 0; m >>= 1) A += __shfl_xor(A, m, 64);

    const float* wr_ = w + (size_t)C1 * D_;
    double ss = 0.0;
#pragma unroll
    for (int i = 0; i < 4; i++) ss += f[i] * (double)wr_[lane + 64 * i];
    for (int m = 32; m > 0; m >>= 1) ss += __shfl_xor(ss, m, 64);
    if (lane == 0) { sampled[n] = (A + Bw[C1]) - 2.0 * ss; idxf[n] = C1; }
}

// ---------------- Slow rows: compacted exact f64 full scan -------------
__launch_bounds__(256)
__global__ void k_slow(const float* __restrict__ x, const float* __restrict__ gam,
                       const float* __restrict__ bet, const float* __restrict__ w,
                       const double* __restrict__ Bw,
                       const int* __restrict__ slowL, const unsigned* __restrict__ slowC,
                       double* __restrict__ sampled, int* __restrict__ idxf) {
    __shared__ double bmS[4];
    __shared__ int    bcS[4];
    int lane = threadIdx.x & 63, wv = threadIdx.x >> 6;
    int cnt = (int)*slowC;
    for (int it = blockIdx.x; it < cnt; it += gridDim.x) {
        int n = slowL[it];
        const float* row = x + (size_t)n * D_;
        float4 xv4 = *(const float4*)(row + lane * 4);
        float4 gv4 = *(const float4*)(gam + lane * 4);
        float4 bv4 = *(const float4*)(bet + lane * 4);
        double xv[4] = {(double)xv4.x, (double)xv4.y, (double)xv4.z, (double)xv4.w};
        double gv[4] = {(double)gv4.x, (double)gv4.y, (double)gv4.z, (double)gv4.w};
        double bv[4] = {(double)bv4.x, (double)bv4.y, (double)bv4.z, (double)bv4.w};
        double s = xv[0] + xv[1] + xv[2] + xv[3];
        for (int m = 32; m > 0; m >>= 1) s += __shfl_xor(s, m, 64);
        double mu = s / 256.0, vs = 0.0;
#pragma unroll
        for (int i = 0; i < 4; i++) { double c = xv[i] - mu; vs += c * c; }
        for (int m = 32; m > 0; m >>= 1) vs += __shfl_xor(vs, m, 64);
        double inv = 1.0 / sqrt(vs / 256.0 + 1e-5);
        double f[4], A = 0.0;
#pragma unroll
        for (int i = 0; i < 4; i++) {
            f[i] = (xv[i] - mu) * inv * gv[i] + bv[i];
            A += f[i] * f[i];
        }
        for (int m = 32; m > 0; m >>= 1) A += __shfl_xor(A, m, 64);

        double bm = 1.0e300; int bc = 0x7fffffff;
        int cbase = wv * 256;
#pragma unroll 2
        for (int c = cbase; c < cbase + 256; c++) {
            float4 w4 = *(const float4*)(w + (size_t)c * D_ + lane * 4);
            double ss = f[0] * (double)w4.x + f[1] * (double)w4.y
                      + f[2] * (double)w4.z + f[3] * (double)w4.w;
            for (int m = 32; m > 0; m >>= 1) ss += __shfl_xor(ss, m, 64);
            double dist = (A + Bw[c]) - 2.0 * ss;
            if (dist < bm) { bm = dist; bc = c; }
        }
        if (lane == 0) { bmS[wv] = bm; bcS[wv] = bc; }
        __syncthreads();
        if (threadIdx.x == 0) {
            double M = bmS[0]; int C = bcS[0];
            for (int i = 1; i < 4; i++)
                if (bmS[i] < M || (bmS[i] == M && bcS[i] < C)) { M = bmS[i]; C = bcS[i]; }
            sampled[n] = M; idxf[n] = C;
        }
        __syncthreads();
    }
}

// ---------------- stable argsort per batch row + enc gather -------------
__launch_bounds__(1024)
__global__ void k_sort(const double* __restrict__ sampled, const int* __restrict__ idxf,
                       int* __restrict__ enc) {
    __shared__ double val[1024];
    __shared__ int    sid[1024];
    int b = blockIdx.x, t = threadIdx.x;
    val[t] = sampled[(size_t)b * S_ + t];
    sid[t] = t;
    __syncthreads();
    for (int k = 2; k <= 1024; k <<= 1) {
        for (int j = k >> 1; j > 0; j >>= 1) {
            int p = t ^ j;
            if (p > t) {
                double v0 = val[t], v1 = val[p];
                int i0 = sid[t], i1 = sid[p];
                bool gtv = (v0 > v1) || (v0 == v1 && i0 > i1);
                bool asc = ((t & k) == 0);
                if (asc ? gtv : !gtv) {
                    val[t] = v1; val[p] = v0; sid[t] = i1; sid[p] = i0;
                }
            }
            __syncthreads();
        }
    }
    enc[(size_t)b * S_ + t] = idxf[sid[t]];   // faithful reference flat-index bug
}

// ---------------- gather: quantized out, idx out, counts, per-row loss -------------
__global__ void k_gather(const float* __restrict__ x, const float* __restrict__ w,
                         const int* __restrict__ enc, float* __restrict__ out,
                         unsigned* __restrict__ cnt, double* __restrict__ lossP) {
    int lane = threadIdx.x & 63, wv = threadIdx.x >> 6;
    int n = blockIdx.x * 4 + wv;
    int e = enc[n];
    const float* wr_ = w + (size_t)e * D_;
    const float* xr = x + (size_t)n * D_;
    float* qr = out + O_Q + (size_t)n * D_;
    double ls = 0.0;
#pragma unroll
    for (int i = 0; i < 4; i++) {
        int d = lane + 64 * i;
        float q = wr_[d], xv = xr[d];
        qr[d] = q;
        double df = (double)q - (double)xv;
        ls += df * df;
    }
    for (int m = 32; m > 0; m >>= 1) ls += __shfl_xor(ls, m, 64);
    if (lane == 0) {
        lossP[n] = ls;
        out[O_IDX + n] = (float)e;
        atomicAdd(&cnt[e], 1u);
    }
}

// ---------------- finalize (+ fused prefix scan for CSR) -------------
__launch_bounds__(1024)
__global__ void k_final(const unsigned* __restrict__ cnt, const float* __restrict__ ema_cs,
                        const double* __restrict__ lossP, float* __restrict__ out,
                        float* __restrict__ csf, int* __restrict__ starts,
                        int* __restrict__ pos) {
    __shared__ double red[1024];
    __shared__ int sc[1024];
    int t = threadIdx.x;
    int cv = (int)cnt[t];
    float cf = (float)cv;
    float cs0 = 0.99f * ema_cs[t] + 0.01f * cf;
    red[t] = (double)cs0;
    sc[t] = cv;
    __syncthreads();
    for (int s = 512; s > 0; s >>= 1) { if (t < s) red[t] += red[t + s]; __syncthreads(); }
    double ntot = red[0];
    __syncthreads();
    double c2 = ((double)cs0 + 1e-5) / (ntot + 1024.0 * 1e-5) * ntot;
    out[O_NCS + t] = (float)c2;
    csf[t] = (float)c2;
    double p = (double)cf / 32768.0;
    red[t] = -p * log(p + 1e-10);
    __syncthreads();
    for (int s = 512; s > 0; s >>= 1) { if (t < s) red[t] += red[t + s]; __syncthreads(); }
    double ent = red[0];
    __syncthreads();
    double ls = 0.0;
    for (int i = 0; i < 32; i++) ls += lossP[t + 1024 * i];
    red[t] = ls;
    __syncthreads();
    for (int s = 512; s > 0; s >>= 1) { if (t < s) red[t] += red[t + s]; __syncthreads(); }
    if (t == 0) {
        out[O_PERP] = (float)exp(ent);
        out[O_LOSS] = (float)(1.25 * red[0] / 8388608.0);
    }
    // prefix scan of counts -> starts/pos
    for (int off = 1; off < 1024; off <<= 1) {
        int add = (t >= off) ? sc[t - off] : 0;
        __syncthreads();
        sc[t] += add;
        __syncthreads();
    }
    int excl = sc[t] - cv;
    starts[t] = excl;
    pos[t] = excl;
    if (t == 1023) starts[1024] = sc[t];
}

__global__ void k_fill(const int* __restrict__ enc, int* __restrict__ pos,
                       int* __restrict__ rowl) {
    int n = blockIdx.x * 256 + threadIdx.x;
    int p = atomicAdd(&pos[enc[n]], 1);
    rowl[p] = n;
}

// ---------------- dw gather-sum + EMA + new_weight -------------
__global__ void k_dwsum(const float* __restrict__ x, const float* __restrict__ ema_w,
                        const int* __restrict__ rowl, const int* __restrict__ starts,
                        const float* __restrict__ csf, float* __restrict__ out) {
    int k = blockIdx.x, d = threadIdx.x;
    int s0 = starts[k], s1 = starts[k + 1];
    float acc = 0.0f;
    for (int i = s0; i < s1; i++) {
        int rr = rowl[i];
        acc += x[(size_t)rr * D_ + d];
    }
    size_t idx = (size_t)k * D_ + d;
    float ne = 0.99f * ema_w[idx] + 0.01f * acc;
    out[O_NEW + idx] = ne;
    out[O_NW + idx] = ne / csf[k];
}

extern "C" void kernel_launch(void* const* d_in, const int* in_sizes, int n_in,
                              void* d_out, int out_size, void* d_ws, size_t ws_size,
                              hipStream_t stream) {
    (void)in_sizes; (void)n_in; (void)out_size; (void)ws_size;
    const float* x      = (const float*)d_in[0];
    const float* w      = (const float*)d_in[1];
    const float* ema_w  = (const float*)d_in[2];
    const float* ema_cs = (const float*)d_in[3];
    const float* g      = (const float*)d_in[4];
    const float* bt     = (const float*)d_in[5];
    float* out = (float*)d_out;
    char* ws = (char*)d_ws;

    __bf16* fh   = (__bf16*)(ws + OFF_FH);
    __bf16* fl   = (__bf16*)(ws + OFF_FL);
    __bf16* wh   = (__bf16*)(ws + OFF_WH);
    __bf16* wl   = (__bf16*)(ws + OFF_WL);
    double* Bw   = (double*)(ws + OFF_BW);
    float*  Bwf  = (float*)(ws + OFF_BWF);
    double* samp = (double*)(ws + OFF_SAMP);
    int*    idxf = (int*)(ws + OFF_IDXF);
    int*    enc  = (int*)(ws + OFF_ENC);
    unsigned* cnt = (unsigned*)(ws + OFF_CNT);
    unsigned* slowC = (unsigned*)(ws + OFF_SLOWC);
    int*    slowL = (int*)(ws + OFF_SLOWL);
    double* lossP = (double*)(ws + OFF_LOSSP);
    int*    rowl = (int*)(ws + OFF_ROWL);
    int*    st   = (int*)(ws + OFF_ST);
    int*    pos  = (int*)(ws + OFF_POS);
    float*  csf  = (float*)(ws + OFF_CSF);

    (void)hipMemsetAsync(ws + OFF_CNT, 0, 4160, stream);   // cnt + slowC

    k_ln<<<N_ / 4, 256, 0, stream>>>(x, g, bt, fh, fl);
    k_bw<<<K_ / 4, 256, 0, stream>>>(w, Bw, Bwf, wh, wl);
    k_phase1<<<2048, 256, 0, stream>>>(fh, fl, wh, wl, Bwf, out);  // partials in out-Q (dead region)
    k_phase2<<<N_ / 4, 256, 0, stream>>>(x, g, bt, w, Bw, out, samp, idxf, slowC, slowL);
    k_slow<<<256, 256, 0, stream>>>(x, g, bt, w, Bw, slowL, slowC, samp, idxf);
    k_sort<<<B_, 1024, 0, stream>>>(samp, idxf, enc);
    k_gather<<<N_ / 4, 256, 0, stream>>>(x, w, enc, out, cnt, lossP);
    k_final<<<1, 1024, 0, stream>>>(cnt, ema_cs, lossP, out, csf, st, pos);
    k_fill<<<N_ / 256, 256, 0, stream>>>(enc, pos, rowl);
    k_dwsum<<<K_, 256, 0, stream>>>(x, ema_w, rowl, st, csf, out);
}